// Round 5
// baseline (336.824 us; speedup 1.0000x reference)
//
#include <hip/hip_runtime.h>
#include <hip/hip_bf16.h>
#include <stdint.h>

typedef unsigned short u16;
typedef __bf16 bf16x8 __attribute__((ext_vector_type(8)));
typedef float floatx4 __attribute__((ext_vector_type(4)));

#define B_SZ 64
#define T_SZ 1024
#define NK 500

// f32 -> bf16, round-to-nearest-even
__device__ __forceinline__ u16 f2bf(float f) {
    union { float f; uint32_t u; } v; v.f = f;
    uint32_t u = v.u;
    u += 0x7FFFu + ((u >> 16) & 1u);
    return (u16)(u >> 16);
}

// HW transcendentals: v_exp_f32 (2^x), v_log_f32 (log2 x)
__device__ __forceinline__ float exp2_hw(float x) { return __builtin_amdgcn_exp2f(x); }
__device__ __forceinline__ float log2_hw(float x) { return __builtin_amdgcn_logf(x); }

// fast stable 2-way logsumexp
__device__ __forceinline__ float lse2(float a, float b) {
    float m = fmaxf(a, b);
    float d = fabsf(a - b);
    return fmaf(0.6931471805599453f,
                log2_hw(1.0f + exp2_hw(-d * 1.4426950408889634f)), m);
}

// -------- kernel 0: pack W1 f32 [K=512][N=512] into MFMA-fragment order ------
// Fragment (ntile 0..31, ks 0..15) is 1 KB CONTIGUOUS: for lane l = g*16+col,
//   W1P[((ntile*16+ks)*64 + l)*8 + j] = W1[ks*32+g*8+j][ntile*16+col].
// Why: the strided B-loads (16 B/lane, lane-stride 1024 B) put all 16 line
// requests of every load on the same few L2 channels (addresses differ only in
// bit>=10). 512 MB/dispatch of B-line traffic at ~1/4 of L2 channel BW ~= the
// ~125 us plateau observed in r0-r4, invariant to occupancy (r1), compiler
// prefetch (r3) and forced asm pipelining (r4). Contiguous 1 KB fragments
// spread across 8 consecutive lines -> full channel interleave, 2x fewer
// transactions. (r2 tested this but its profile window was polluted by a
// 161 MB host upload; layout verified correct there, passed=true.)
__global__ __launch_bounds__(256) void pack_w1(const float* __restrict__ in,
                                               u16* __restrict__ out) {
    int idx = blockIdx.x * 256 + threadIdx.x;   // 0..32767 = (ntile, ks, lane)
    int l     = idx & 63;
    int ks    = (idx >> 6) & 15;
    int ntile = idx >> 10;
    int col = l & 15, gg = l >> 4;
    int n = ntile * 16 + col;
    int kbase = ks * 32 + gg * 8;
    union { uint4 v; u16 s[8]; } p;
#pragma unroll
    for (int j = 0; j < 8; ++j)
        p.s[j] = f2bf(in[(size_t)(kbase + j) * 512 + n]);
    *(uint4*)(out + (size_t)idx * 8) = p.v;
}

// -------- kernel 1: fused MLP o = tanh(FM@W1+b1)@W2+b2 --------
// Exactly the round-1 kernel (best so far, 122.5 us) with B reads switched to
// the packed-fragment layout: per (ni,ks) one contiguous 1 KB dwordx4 load.
// 1024 blocks x 512 thr (8 waves), block = 64 rows x N=512, wave 64x64,
// 2-slot compiler-scheduled double buffer.
__global__ __launch_bounds__(512, 4) void mlp_fused(
    const float* __restrict__ FM, const u16* __restrict__ W1P,
    const float* __restrict__ b1, const float* __restrict__ W2,
    const float* __restrict__ b2, float* __restrict__ o_buf) {

    __shared__ __align__(16) u16 ldsA[64 * 512];   // 64 KB, swizzle: k8 ^= (row&7)
    __shared__ float ldsO[64][8][2];               // 4 KB

    const int tid  = threadIdx.x;
    const int w    = tid >> 6;       // wave 0..7
    const int lane = tid & 63;
    const int col  = lane & 15;
    const int g    = lane >> 4;
    const size_t row0 = (size_t)blockIdx.x * 64;

    // ---- stage A once: 64 rows x 512 k, f32 -> bf16, xor-swizzled ----
#pragma unroll
    for (int i = 0; i < 8; ++i) {
        int flat = i * 512 + tid;        // 8-elem group index, 0..4095
        int row  = flat >> 6;            // 0..63
        int k8   = flat & 63;            // 0..63
        const float* src = FM + (row0 + row) * 512 + k8 * 8;
        float4 f0 = ((const float4*)src)[0];
        float4 f1 = ((const float4*)src)[1];
        union { uint4 v; u16 s[8]; } p;
        p.s[0] = f2bf(f0.x); p.s[1] = f2bf(f0.y);
        p.s[2] = f2bf(f0.z); p.s[3] = f2bf(f0.w);
        p.s[4] = f2bf(f1.x); p.s[5] = f2bf(f1.y);
        p.s[6] = f2bf(f1.z); p.s[7] = f2bf(f1.w);
        int sw = k8 ^ (row & 7);
        *(uint4*)(ldsA + row * 512 + sw * 8) = p.v;
    }
    __syncthreads();   // the ONLY barrier before the epilogue

    // packed-B base: fragment (ni,ks) of wave w at +(w*64 + ni*16 + ks)*512 elems
    const u16* bbase = W1P + ((size_t)(w * 64) * 64 + lane) * 8;

    floatx4 acc[4][4];
    floatx4 zero = {0.f, 0.f, 0.f, 0.f};
#pragma unroll
    for (int mi = 0; mi < 4; mi++)
#pragma unroll
        for (int ni = 0; ni < 4; ni++) acc[mi][ni] = zero;

    bf16x8 bA[4], bB[4];
#pragma unroll
    for (int ni = 0; ni < 4; ni++)
        bA[ni] = *(const bf16x8*)(bbase + (ni * 16 + 0) * 512);     // ks=0

    for (int ks2 = 0; ks2 < 16; ks2 += 2) {
        // prefetch ks2+1 into bB
#pragma unroll
        for (int ni = 0; ni < 4; ni++)
            bB[ni] = *(const bf16x8*)(bbase + (ni * 16 + ks2 + 1) * 512);
        {   // compute ks2 with bA
            bf16x8 afr[4];
            int sw = (ks2 * 4 + g) ^ (col & 7);
#pragma unroll
            for (int mi = 0; mi < 4; mi++)
                afr[mi] = *(const bf16x8*)(ldsA + (mi * 16 + col) * 512 + sw * 8);
#pragma unroll
            for (int mi = 0; mi < 4; mi++)
#pragma unroll
                for (int ni = 0; ni < 4; ni++)
                    acc[mi][ni] = __builtin_amdgcn_mfma_f32_16x16x32_bf16(
                        afr[mi], bA[ni], acc[mi][ni], 0, 0, 0);
        }
        // prefetch ks2+2 into bA (ks2+2==16 wraps to ks=0, harmless reload)
        int ksn = (ks2 + 2) & 15;
#pragma unroll
        for (int ni = 0; ni < 4; ni++)
            bA[ni] = *(const bf16x8*)(bbase + (ni * 16 + ksn) * 512);
        {   // compute ks2+1 with bB
            bf16x8 afr[4];
            int sw = ((ks2 + 1) * 4 + g) ^ (col & 7);
#pragma unroll
            for (int mi = 0; mi < 4; mi++)
                afr[mi] = *(const bf16x8*)(ldsA + (mi * 16 + col) * 512 + sw * 8);
#pragma unroll
            for (int mi = 0; mi < 4; mi++)
#pragma unroll
                for (int ni = 0; ni < 4; ni++)
                    acc[mi][ni] = __builtin_amdgcn_mfma_f32_16x16x32_bf16(
                        afr[mi], bB[ni], acc[mi][ni], 0, 0, 0);
        }
    }

    // epilogue: h = tanh(acc + b1[n]); fold into W2 reduction
    float po[4][4][2];
#pragma unroll
    for (int mi = 0; mi < 4; mi++)
#pragma unroll
        for (int r = 0; r < 4; r++) { po[mi][r][0] = 0.f; po[mi][r][1] = 0.f; }

#pragma unroll
    for (int ni = 0; ni < 4; ni++) {
        int n = w * 64 + ni * 16 + col;
        float b1f = b1[n];
        float w20 = W2[2 * n], w21 = W2[2 * n + 1];
#pragma unroll
        for (int mi = 0; mi < 4; mi++)
#pragma unroll
            for (int r = 0; r < 4; r++) {
                float x = acc[mi][ni][r] + b1f;
                float ax = fabsf(x);
                float e = exp2_hw(-2.885390082f * ax);   // exp(-2ax)
                float t = (1.f - e) / (1.f + e);
                float h = copysignf(t, x);
                po[mi][r][0] += h * w20;
                po[mi][r][1] += h * w21;
            }
    }

    // reduce po over the 16 cols (lane bits 0..3)
#pragma unroll
    for (int mi = 0; mi < 4; mi++)
#pragma unroll
        for (int r = 0; r < 4; r++)
#pragma unroll
            for (int j = 0; j < 2; j++) {
                float v = po[mi][r][j];
                v += __shfl_xor(v, 1, 64);
                v += __shfl_xor(v, 2, 64);
                v += __shfl_xor(v, 4, 64);
                v += __shfl_xor(v, 8, 64);
                po[mi][r][j] = v;
            }
    if (col == 0) {
#pragma unroll
        for (int mi = 0; mi < 4; mi++)
#pragma unroll
            for (int r = 0; r < 4; r++) {
                int row = mi * 16 + g * 4 + r;      // 0..63
                ldsO[row][w][0] = po[mi][r][0];
                ldsO[row][w][1] = po[mi][r][1];
            }
    }
    __syncthreads();
    if (tid < 128) {           // 64 rows x 2 outputs
        int row = tid >> 1, j = tid & 1;
        float v = ldsO[row][0][j] + ldsO[row][1][j]
                + ldsO[row][2][j] + ldsO[row][3][j]
                + ldsO[row][4][j] + ldsO[row][5][j]
                + ldsO[row][6][j] + ldsO[row][7][j] + b2[j];
        o_buf[(row0 + row) * 2 + j] = v;
    }
}

// -------- kernel 2: per-(b,chain) HMM recurrence, ballot-mask driven --------
// grid 64*8 blocks of 64 threads: block (b, g) owns chains c = g*64+lane.
__global__ __launch_bounds__(64) void bkt_scan(
    const int* __restrict__ corr, const int* __restrict__ kc,
    const float* __restrict__ trans_logits,
    const float* __restrict__ obs_logits,
    const float* __restrict__ init_logits,
    const float* __restrict__ o_buf,
    float* __restrict__ out) {

    __shared__ int s_kc[T_SZ];
    __shared__ int s_corr[T_SZ];
    __shared__ float2 s_o[T_SZ];
    const int b = blockIdx.x >> 3;
    const int g = blockIdx.x & 7;
    const int lane = threadIdx.x;

#pragma unroll
    for (int i = 0; i < 4; ++i) {
        int t4 = i * 64 + lane;   // int4 group
        ((int4*)s_kc)[t4]   = ((const int4*)(kc + b * T_SZ))[t4];
        ((int4*)s_corr)[t4] = ((const int4*)(corr + b * T_SZ))[t4];
    }
#pragma unroll
    for (int i = 0; i < 8; ++i) {
        int t4 = i * 64 + lane;   // float4 group (2 timesteps)
        ((float4*)s_o)[t4] = ((const float4*)(o_buf + (size_t)b * T_SZ * 2))[t4];
    }
    __syncthreads();

    const int c  = g * 64 + lane;
    const int cp = c < NK ? c : NK - 1;    // clamp for param loads (lanes c>=500 inert)

    float ob00 = obs_logits[cp * 4 + 0], ob01 = obs_logits[cp * 4 + 1];
    float ob10 = obs_logits[cp * 4 + 2], ob11 = obs_logits[cp * 4 + 3];
    float tr00 = trans_logits[cp * 4 + 0], tr01 = trans_logits[cp * 4 + 1];
    float tr10 = trans_logits[cp * 4 + 2], tr11 = trans_logits[cp * 4 + 3];
    float n0 = lse2(tr00, tr10), n1 = lse2(tr01, tr11);
    float lt00 = tr00 - n0, lt01 = tr01 - n1;
    float lt10 = tr10 - n0, lt11 = tr11 - n1;
    float i0 = init_logits[cp * 2], i1 = init_logits[cp * 2 + 1];
    float nli = lse2(i0, i1);
    float la0 = i0 - nli, la1 = i1 - nli;

    for (int w16 = 0; w16 < 16; ++w16) {
        int tl = w16 * 64 + lane;
        unsigned long long mask = __ballot((s_kc[tl] >> 6) == g);
        while (mask) {
            int tz = __builtin_ctzll(mask);
            mask &= mask - 1;
            int t = w16 * 64 + tz;
            int kct = s_kc[t];
            if (c == kct) {
                float o0 = s_o[t].x, o1 = s_o[t].y;
                float x00 = ob00 + o0, x01 = ob01 - o0;
                float x10 = ob10 + o1, x11 = ob11 - o1;
                float d0 = lse2(x00, x01), d1 = lse2(x10, x11);
                float lo00 = x00 - d0, lo01 = x01 - d0;
                float lo10 = x10 - d1, lo11 = x11 - d1;
                float py0 = lse2(lo00 + la0, lo10 + la1);
                float py1 = lse2(lo01 + la0, lo11 + la1);
                float pn = lse2(py0, py1);
                ((float2*)out)[(size_t)b * T_SZ + t] = make_float2(py0 - pn, py1 - pn);
                float lp0 = s_corr[t] ? lo01 : lo00;
                float lp1 = s_corr[t] ? lo11 : lo10;
                float t0 = lp0 + la0, t1 = lp1 + la1;
                float nla0 = lse2(t0 + lt00, t1 + lt01);
                float nla1 = lse2(t0 + lt10, t1 + lt11);
                la0 = nla0; la1 = nla1;
            }
        }
    }
}

extern "C" void kernel_launch(void* const* d_in, const int* in_sizes, int n_in,
                              void* d_out, int out_size, void* d_ws, size_t ws_size,
                              hipStream_t stream) {
    const int*   corr = (const int*)d_in[0];
    const int*   kc   = (const int*)d_in[1];
    const float* FM   = (const float*)d_in[2];
    const float* W1   = (const float*)d_in[3];
    const float* b1   = (const float*)d_in[4];
    const float* W2   = (const float*)d_in[5];
    const float* b2   = (const float*)d_in[6];
    const float* trans_logits = (const float*)d_in[7];
    const float* obs_logits   = (const float*)d_in[8];
    const float* init_logits  = (const float*)d_in[9];
    float* out = (float*)d_out;

    u16*   w1p   = (u16*)d_ws;                                  // 512 KB packed W1
    float* o_buf = (float*)((char*)d_ws + 512 * 512 * 2);       // 512 KB

    pack_w1<<<128, 256, 0, stream>>>(W1, w1p);
    mlp_fused<<<1024, 512, 0, stream>>>(FM, w1p, b1, W2, b2, o_buf);
    bkt_scan<<<B_SZ * 8, 64, 0, stream>>>(corr, kc, trans_logits, obs_logits,
                                          init_logits, o_buf, out);
}

// Round 6
// 304.570 us; speedup vs baseline: 1.1059x; 1.1059x over previous
//
#include <hip/hip_runtime.h>
#include <hip/hip_bf16.h>
#include <stdint.h>

typedef unsigned short u16;
typedef __bf16 bf16x8 __attribute__((ext_vector_type(8)));
typedef float floatx4 __attribute__((ext_vector_type(4)));

#define B_SZ 64
#define T_SZ 1024
#define NK 500

// f32 -> bf16, round-to-nearest-even
__device__ __forceinline__ u16 f2bf(float f) {
    union { float f; uint32_t u; } v; v.f = f;
    uint32_t u = v.u;
    u += 0x7FFFu + ((u >> 16) & 1u);
    return (u16)(u >> 16);
}

__device__ __forceinline__ float exp2_hw(float x) { return __builtin_amdgcn_exp2f(x); }
__device__ __forceinline__ float log2_hw(float x) { return __builtin_amdgcn_logf(x); }

// fast stable 2-way logsumexp
__device__ __forceinline__ float lse2(float a, float b) {
    float m = fmaxf(a, b);
    float d = fabsf(a - b);
    return fmaf(0.6931471805599453f,
                log2_hw(1.0f + exp2_hw(-d * 1.4426950408889634f)), m);
}

// direct global->LDS DMA, 16 B per lane. LDS dest = wave-uniform base +
// lane*16 (HW); global source is per-lane. Tracked by vmcnt.
__device__ __forceinline__ void gload_lds16(const u16* g, u16* l) {
    __builtin_amdgcn_global_load_lds(
        (const __attribute__((address_space(1))) unsigned int*)g,
        (__attribute__((address_space(3))) unsigned int*)l,
        16, 0, 0);
}

// -------- kernel 0: pack W1 f32 [K=512][N=512] into MFMA-fragment order ------
// Fragment (ntile 0..31, ks 0..15) is 1 KB CONTIGUOUS: for lane l = g*16+col,
//   W1P[((ntile*16+ks)*64 + l)*8 + j] = W1[ks*32+g*8+j][ntile*16+col].
// (verified passing in r2 and r5)
__global__ __launch_bounds__(256) void pack_w1(const float* __restrict__ in,
                                               u16* __restrict__ out) {
    int idx = blockIdx.x * 256 + threadIdx.x;   // 0..32767 = (ntile, ks, lane)
    int l     = idx & 63;
    int ks    = (idx >> 6) & 15;
    int ntile = idx >> 10;
    int col = l & 15, gg = l >> 4;
    int n = ntile * 16 + col;
    int kbase = ks * 32 + gg * 8;
    union { uint4 v; u16 s[8]; } p;
#pragma unroll
    for (int j = 0; j < 8; ++j)
        p.s[j] = f2bf(in[(size_t)(kbase + j) * 512 + n]);
    *(uint4*)(out + (size_t)idx * 8) = p.v;
}

// -------- kernel 1: fused MLP o = tanh(FM@W1+b1)@W2+b2 --------
// r6 structure: B comes through LDS via global_load_lds DMA (one instruction
// per 1 KB fragment, no VGPR roundtrip, no per-lane 16-line scatter). r0-r5
// invariance (122-140 us, MfmaUtil ~10% across occupancy x2, pipeline depth
// x3, two layouts) indicts per-CU VMEM transaction occupancy (~33K line-
// transactions x ~6cy ~= the plateau); DMA cuts B's instruction+transaction
// path by ~16x. Per-wave-exclusive LDS slices -> NO barriers in the K-loop;
// per-wave counted vmcnt(4) (never 0 until tail). Per-block K-phase rotation
// kv=(t+bid)&15 kills the packed-layout convoy seen in r2/r5 (fp sum order
// change only). LDS 132 KB -> 1 block/CU (occupancy proven non-binding r0-r1).
__global__ __launch_bounds__(512, 2) void mlp_fused(
    const float* __restrict__ FM, const u16* __restrict__ W1P,
    const float* __restrict__ b1, const float* __restrict__ W2,
    const float* __restrict__ b2, float* __restrict__ o_buf) {

    __shared__ __align__(16) u16 ldsA[64 * 512];      // 64 KB, swz k8 ^= (row&7)
    __shared__ __align__(16) u16 ldsB[2][32 * 512];   // 2 x 32 KB, frag-linear
    __shared__ float ldsO[64][8][2];                  // 4 KB

    const int tid  = threadIdx.x;
    const int w    = tid >> 6;       // wave 0..7
    const int lane = tid & 63;
    const int col  = lane & 15;
    const int g    = lane >> 4;
    const size_t row0 = (size_t)blockIdx.x * 64;
    const int kb = blockIdx.x & 15;  // per-block k-phase rotation

    // ---- stage A once: 64 rows x 512 k, f32 -> bf16, xor-swizzled ----
#pragma unroll
    for (int i = 0; i < 8; ++i) {
        int flat = i * 512 + tid;
        int row  = flat >> 6;
        int k8   = flat & 63;
        const float* src = FM + (row0 + row) * 512 + k8 * 8;
        float4 f0 = ((const float4*)src)[0];
        float4 f1 = ((const float4*)src)[1];
        union { uint4 v; u16 s[8]; } p;
        p.s[0] = f2bf(f0.x); p.s[1] = f2bf(f0.y);
        p.s[2] = f2bf(f0.z); p.s[3] = f2bf(f0.w);
        p.s[4] = f2bf(f1.x); p.s[5] = f2bf(f1.y);
        p.s[6] = f2bf(f1.z); p.s[7] = f2bf(f1.w);
        int sw = k8 ^ (row & 7);
        *(uint4*)(ldsA + row * 512 + sw * 8) = p.v;
    }
    __syncthreads();   // A visible to all waves (A-uses are cross-wave; B is not)

    // wave-local B bases. Fragment (ni,kv) of wave w lives at
    // W1P elem ((w*4+ni)*16 + kv) * 512; LDS slice (w*4+ni)*512 in buf.
    const u16* wbase = W1P + (size_t)(w * 4) * 16 * 512 + lane * 8;
    u16* lb[2] = { &ldsB[0][(w * 4) * 512], &ldsB[1][(w * 4) * 512] };

    floatx4 acc[4][4];
    floatx4 zero = {0.f, 0.f, 0.f, 0.f};
#pragma unroll
    for (int mi = 0; mi < 4; mi++)
#pragma unroll
        for (int ni = 0; ni < 4; ni++) acc[mi][ni] = zero;

#define STAGEB(LB, KV) do {                                        \
        const u16* gp_ = wbase + (size_t)(KV) * 512;               \
        gload_lds16(gp_ + 0 * 16 * 512, (LB) + 0 * 512);           \
        gload_lds16(gp_ + 1 * 16 * 512, (LB) + 1 * 512);           \
        gload_lds16(gp_ + 2 * 16 * 512, (LB) + 2 * 512);           \
        gload_lds16(gp_ + 3 * 16 * 512, (LB) + 3 * 512);           \
    } while (0)

    // prologue: 2 fragments-sets (8 DMAs) in flight
    STAGEB(lb[0], kb);
    STAGEB(lb[1], (kb + 1) & 15);

#pragma unroll
    for (int t = 0; t < 16; ++t) {
        u16* cur = lb[t & 1];
        // wait current buffer's 4 DMAs landed (4 newer stay in flight)
        if (t < 15) { asm volatile("s_waitcnt vmcnt(4)" ::: "memory"); }
        else        { asm volatile("s_waitcnt vmcnt(0)" ::: "memory"); }
        __builtin_amdgcn_sched_barrier(0);

        int kv = (t + kb) & 15;
        bf16x8 bB[4], afr[4];
#pragma unroll
        for (int ni = 0; ni < 4; ni++)
            bB[ni] = *(const bf16x8*)(cur + ni * 512 + lane * 8);
        int sw = (kv * 4 + g) ^ (col & 7);
#pragma unroll
        for (int mi = 0; mi < 4; mi++)
            afr[mi] = *(const bf16x8*)(ldsA + (mi * 16 + col) * 512 + sw * 8);

        // reads retired -> safe to overwrite this buffer with kv(t+2)
        asm volatile("s_waitcnt lgkmcnt(0)" ::: "memory");
        __builtin_amdgcn_sched_barrier(0);
        if (t < 14) STAGEB(cur, (t + 2 + kb) & 15);

#pragma unroll
        for (int mi = 0; mi < 4; mi++)
#pragma unroll
            for (int ni = 0; ni < 4; ni++)
                acc[mi][ni] = __builtin_amdgcn_mfma_f32_16x16x32_bf16(
                    afr[mi], bB[ni], acc[mi][ni], 0, 0, 0);
    }
#undef STAGEB

    // epilogue: h = tanh(acc + b1[n]); fold into W2 reduction
    float po[4][4][2];
#pragma unroll
    for (int mi = 0; mi < 4; mi++)
#pragma unroll
        for (int r = 0; r < 4; r++) { po[mi][r][0] = 0.f; po[mi][r][1] = 0.f; }

#pragma unroll
    for (int ni = 0; ni < 4; ni++) {
        int n = w * 64 + ni * 16 + col;
        float b1f = b1[n];
        float w20 = W2[2 * n], w21 = W2[2 * n + 1];
#pragma unroll
        for (int mi = 0; mi < 4; mi++)
#pragma unroll
            for (int r = 0; r < 4; r++) {
                float x = acc[mi][ni][r] + b1f;
                float ax = fabsf(x);
                float e = exp2_hw(-2.885390082f * ax);   // exp(-2ax)
                float t = (1.f - e) / (1.f + e);
                float h = copysignf(t, x);
                po[mi][r][0] += h * w20;
                po[mi][r][1] += h * w21;
            }
    }

#pragma unroll
    for (int mi = 0; mi < 4; mi++)
#pragma unroll
        for (int r = 0; r < 4; r++)
#pragma unroll
            for (int j = 0; j < 2; j++) {
                float v = po[mi][r][j];
                v += __shfl_xor(v, 1, 64);
                v += __shfl_xor(v, 2, 64);
                v += __shfl_xor(v, 4, 64);
                v += __shfl_xor(v, 8, 64);
                po[mi][r][j] = v;
            }
    if (col == 0) {
#pragma unroll
        for (int mi = 0; mi < 4; mi++)
#pragma unroll
            for (int r = 0; r < 4; r++) {
                int row = mi * 16 + g * 4 + r;      // 0..63
                ldsO[row][w][0] = po[mi][r][0];
                ldsO[row][w][1] = po[mi][r][1];
            }
    }
    __syncthreads();
    if (tid < 128) {           // 64 rows x 2 outputs
        int row = tid >> 1, j = tid & 1;
        float v = ldsO[row][0][j] + ldsO[row][1][j]
                + ldsO[row][2][j] + ldsO[row][3][j]
                + ldsO[row][4][j] + ldsO[row][5][j]
                + ldsO[row][6][j] + ldsO[row][7][j] + b2[j];
        o_buf[(row0 + row) * 2 + j] = v;
    }
}

// -------- kernel 2: per-(b,chain) HMM recurrence, ballot-mask driven --------
__global__ __launch_bounds__(64) void bkt_scan(
    const int* __restrict__ corr, const int* __restrict__ kc,
    const float* __restrict__ trans_logits,
    const float* __restrict__ obs_logits,
    const float* __restrict__ init_logits,
    const float* __restrict__ o_buf,
    float* __restrict__ out) {

    __shared__ int s_kc[T_SZ];
    __shared__ int s_corr[T_SZ];
    __shared__ float2 s_o[T_SZ];
    const int b = blockIdx.x >> 3;
    const int g = blockIdx.x & 7;
    const int lane = threadIdx.x;

#pragma unroll
    for (int i = 0; i < 4; ++i) {
        int t4 = i * 64 + lane;
        ((int4*)s_kc)[t4]   = ((const int4*)(kc + b * T_SZ))[t4];
        ((int4*)s_corr)[t4] = ((const int4*)(corr + b * T_SZ))[t4];
    }
#pragma unroll
    for (int i = 0; i < 8; ++i) {
        int t4 = i * 64 + lane;
        ((float4*)s_o)[t4] = ((const float4*)(o_buf + (size_t)b * T_SZ * 2))[t4];
    }
    __syncthreads();

    const int c  = g * 64 + lane;
    const int cp = c < NK ? c : NK - 1;

    float ob00 = obs_logits[cp * 4 + 0], ob01 = obs_logits[cp * 4 + 1];
    float ob10 = obs_logits[cp * 4 + 2], ob11 = obs_logits[cp * 4 + 3];
    float tr00 = trans_logits[cp * 4 + 0], tr01 = trans_logits[cp * 4 + 1];
    float tr10 = trans_logits[cp * 4 + 2], tr11 = trans_logits[cp * 4 + 3];
    float n0 = lse2(tr00, tr10), n1 = lse2(tr01, tr11);
    float lt00 = tr00 - n0, lt01 = tr01 - n1;
    float lt10 = tr10 - n0, lt11 = tr11 - n1;
    float i0 = init_logits[cp * 2], i1 = init_logits[cp * 2 + 1];
    float nli = lse2(i0, i1);
    float la0 = i0 - nli, la1 = i1 - nli;

    for (int w16 = 0; w16 < 16; ++w16) {
        int tl = w16 * 64 + lane;
        unsigned long long mask = __ballot((s_kc[tl] >> 6) == g);
        while (mask) {
            int tz = __builtin_ctzll(mask);
            mask &= mask - 1;
            int t = w16 * 64 + tz;
            int kct = s_kc[t];
            if (c == kct) {
                float o0 = s_o[t].x, o1 = s_o[t].y;
                float x00 = ob00 + o0, x01 = ob01 - o0;
                float x10 = ob10 + o1, x11 = ob11 - o1;
                float d0 = lse2(x00, x01), d1 = lse2(x10, x11);
                float lo00 = x00 - d0, lo01 = x01 - d0;
                float lo10 = x10 - d1, lo11 = x11 - d1;
                float py0 = lse2(lo00 + la0, lo10 + la1);
                float py1 = lse2(lo01 + la0, lo11 + la1);
                float pn = lse2(py0, py1);
                ((float2*)out)[(size_t)b * T_SZ + t] = make_float2(py0 - pn, py1 - pn);
                float lp0 = s_corr[t] ? lo01 : lo00;
                float lp1 = s_corr[t] ? lo11 : lo10;
                float t0 = lp0 + la0, t1 = lp1 + la1;
                float nla0 = lse2(t0 + lt00, t1 + lt01);
                float nla1 = lse2(t0 + lt10, t1 + lt11);
                la0 = nla0; la1 = nla1;
            }
        }
    }
}

extern "C" void kernel_launch(void* const* d_in, const int* in_sizes, int n_in,
                              void* d_out, int out_size, void* d_ws, size_t ws_size,
                              hipStream_t stream) {
    const int*   corr = (const int*)d_in[0];
    const int*   kc   = (const int*)d_in[1];
    const float* FM   = (const float*)d_in[2];
    const float* W1   = (const float*)d_in[3];
    const float* b1   = (const float*)d_in[4];
    const float* W2   = (const float*)d_in[5];
    const float* b2   = (const float*)d_in[6];
    const float* trans_logits = (const float*)d_in[7];
    const float* obs_logits   = (const float*)d_in[8];
    const float* init_logits  = (const float*)d_in[9];
    float* out = (float*)d_out;

    u16*   w1p   = (u16*)d_ws;                                  // 512 KB packed W1
    float* o_buf = (float*)((char*)d_ws + 512 * 512 * 2);       // 512 KB

    pack_w1<<<128, 256, 0, stream>>>(W1, w1p);
    mlp_fused<<<1024, 512, 0, stream>>>(FM, w1p, b1, W2, b2, o_buf);
    bkt_scan<<<B_SZ * 8, 64, 0, stream>>>(corr, kc, trans_logits, obs_logits,
                                          init_logits, o_buf, out);
}